// Round 2
// baseline (430.956 us; speedup 1.0000x reference)
//
#include <hip/hip_runtime.h>
#include <hip/hip_bf16.h>

typedef unsigned short ushort_t;
typedef unsigned int uint_t;
typedef __attribute__((ext_vector_type(4))) float f32x4;
typedef __attribute__((ext_vector_type(8))) short bf16x8;

#define B_DIM 512
#define IN_DIM 4096
#define OUT_DIM 4096
#define BN 32
#define BK 32
#define KSPLIT 8

// ---------- helpers ----------
__device__ __forceinline__ ushort_t f2bf(float f) {
    union { float f; uint_t u; } v; v.f = f;
    uint_t r = v.u + 0x7fffu + ((v.u >> 16) & 1u);   // round-to-nearest-even
    return (ushort_t)(r >> 16);
}

__device__ __forceinline__ void async_copy16(void* lds, const void* g) {
    __builtin_amdgcn_global_load_lds(
        (const __attribute__((address_space(1))) uint_t*)g,
        (__attribute__((address_space(3))) uint_t*)lds, 16, 0, 0);
}

// ---------- kernel 1: x -> bf16 ----------
__global__ __launch_bounds__(256) void conv_x(const float4* __restrict__ X4,
                                              ushort_t* __restrict__ Xb) {
    size_t i = (size_t)blockIdx.x * 256 + threadIdx.x;   // one float4 per thread
    float4 a = X4[i];
    ushort_t r[4] = { f2bf(a.x), f2bf(a.y), f2bf(a.z), f2bf(a.w) };
    *(uint2*)(Xb + i * 4) = *(const uint2*)r;            // 8B/lane coalesced
}

// ---------- kernel 2: fused dequant + split-K GEMM ----------
// Each block owns a full-M (512) x BN(32) output stripe for one K-segment, so
// every U element is fetched from HBM exactly once (no build_w pass, no Wb
// round-trip). B-operand staging: U tile (fp32x4/elem) -> regs -> dequant ->
// bf16 ds_write. A staging via global_load_lds (Xb is L2-resident, 4 MB).
// Wave w computes rows [w*128, w*128+128) x 32 cols: acc[8][2] (64 VGPR).
__global__ __launch_bounds__(256, 3) void gemm_fused(
    const ushort_t* __restrict__ A,   // M x K bf16 (Xb)
    const float4* __restrict__ U4,    // (OUT*IN) float4 rows (p=0..3)
    const float* __restrict__ q,
    const int* __restrict__ expo,
    float* __restrict__ part)         // KSPLIT x M x N fp32
{
    const int M = B_DIM, N = OUT_DIM, K = IN_DIM;
    __shared__ ushort_t sA[B_DIM * BK];   // 512x32 bf16 = 32 KB
    __shared__ ushort_t sW[BN * BK];      // 32x32 bf16 = 2 KB

    const int tid  = threadIdx.x;
    const int lane = tid & 63;
    const int wave = tid >> 6;

    const int n0 = blockIdx.x * BN;
    const int kseg = K / KSPLIT;                       // 512
    const size_t kbase = (size_t)blockIdx.y * kseg;

    const float scale = exp2f((float)expo[0]) * (1.0f / 7.0f);
    const float t0 = q[0] * scale, t1 = q[1] * scale,
                t2 = q[2] * scale, t3 = q[3] * scale;

    // A staging: 8 copies/thread; copy c covers rows [(wave*8+c)*16, +16).
    // lane -> row (lane>>2), 16B chunk (lane&3); LDS offset == lane*16B (linear).
    const ushort_t* gA = A + (size_t)(wave * 128 + (lane >> 2)) * K + kbase + (lane & 3) * 8;
    ushort_t* lA = sA + wave * 128 * BK + lane * 8;

    // U staging: thread t -> W row o = n0 + (t>>3), k-chunk (t&7)*4 (4 elems = 64B)
    const float4* gU = U4 + (size_t)(n0 + (tid >> 3)) * K + kbase + (tid & 7) * 4;
    ushort_t* lW = sW + (tid >> 3) * BK + (tid & 7) * 4;

    // fragment addressing (same mapping as harness-verified round-0 kernel)
    const int quad = lane >> 4;
    const int r16  = lane & 15;
    const ushort_t* fa = sA + (wave * 128 + r16) * BK + quad * 8;
    const ushort_t* fb = sW + r16 * BK + quad * 8;

    f32x4 acc[8][2] = {};

    const int nsteps = kseg / BK;                       // 16
    for (int s = 0; s < nsteps; ++s) {
        // A tile: 32 KB via 8x global_load_lds per thread
#pragma unroll
        for (int c = 0; c < 8; ++c)
            async_copy16(lA + c * 16 * BK, gA + (size_t)c * 16 * K);
        // U tile: 64B/thread to regs, dequant, bf16 ds_write (8B/thread)
        float4 u0 = gU[0], u1 = gU[1], u2 = gU[2], u3 = gU[3];
        gA += BK; gU += BK;
        ushort_t wq[4];
        wq[0] = f2bf(u0.x * t0 + u0.y * t1 + u0.z * t2 + u0.w * t3);
        wq[1] = f2bf(u1.x * t0 + u1.y * t1 + u1.z * t2 + u1.w * t3);
        wq[2] = f2bf(u2.x * t0 + u2.y * t1 + u2.z * t2 + u2.w * t3);
        wq[3] = f2bf(u3.x * t0 + u3.y * t1 + u3.z * t2 + u3.w * t3);
        *(uint2*)lW = *(const uint2*)wq;
        __syncthreads();   // drains vmcnt (A in LDS) + lgkm (sW visible)

        bf16x8 bv0 = *(const bf16x8*)(fb);
        bf16x8 bv1 = *(const bf16x8*)(fb + 16 * BK);
#pragma unroll
        for (int i = 0; i < 8; ++i) {
            bf16x8 av = *(const bf16x8*)(fa + i * 16 * BK);
            acc[i][0] = __builtin_amdgcn_mfma_f32_16x16x32_bf16(av, bv0, acc[i][0], 0, 0, 0);
            acc[i][1] = __builtin_amdgcn_mfma_f32_16x16x32_bf16(av, bv1, acc[i][1], 0, 0, 0);
        }
        __syncthreads();   // all reads done before next iteration's writes
    }

    // epilogue: C/D layout col=lane&15, row=quad*4+reg  [verified m89/m91]
    float* outp = part + (size_t)blockIdx.y * M * N;
#pragma unroll
    for (int i = 0; i < 8; ++i) {
        const int mrow = wave * 128 + i * 16 + quad * 4;
#pragma unroll
        for (int j = 0; j < 2; ++j) {
            const int ncol = n0 + j * 16 + r16;
            float* o = outp + (size_t)mrow * N + ncol;
#pragma unroll
            for (int r = 0; r < 4; ++r)
                o[(size_t)r * N] = acc[i][j][r];
        }
    }
}

// ---------- kernel 3: out = sum_k part[k] + bias ----------
__global__ __launch_bounds__(256) void reduce_bias(const float4* __restrict__ part,
                                                   const float4* __restrict__ bias,
                                                   float4* __restrict__ out) {
    const int MN4 = (B_DIM * OUT_DIM) / 4;   // 524288
    int i = blockIdx.x * 256 + threadIdx.x;
    float4 bb = bias[i & 1023];              // OUT/4 = 1024
    float sx = bb.x, sy = bb.y, sz = bb.z, sw = bb.w;
#pragma unroll
    for (int k = 0; k < KSPLIT; ++k) {
        float4 p = part[i + (size_t)k * MN4];
        sx += p.x; sy += p.y; sz += p.z; sw += p.w;
    }
    float4 o; o.x = sx; o.y = sy; o.z = sz; o.w = sw;
    out[i] = o;
}

extern "C" void kernel_launch(void* const* d_in, const int* in_sizes, int n_in,
                              void* d_out, int out_size, void* d_ws, size_t ws_size,
                              hipStream_t stream) {
    const float* x    = (const float*)d_in[0];   // (512, 4096)
    const float* U    = (const float*)d_in[1];   // (4096*4096, 4)
    const float* q    = (const float*)d_in[2];   // (4,)
    const float* b    = (const float*)d_in[3];   // (4096,)
    const int*   expo = (const int*)d_in[4];     // scalar 0
    float* out = (float*)d_out;

    char* ws = (char*)d_ws;
    ushort_t* Xb  = (ushort_t*)ws;               // 4 MB bf16 (B, IN)
    float*    prt = (float*)(ws + 4194304);      // 64 MB fp32 partials

    // x conversion: 2.09M elems / 4 = 524288 threads
    conv_x<<<2048, 256, 0, stream>>>((const float4*)x, Xb);
    // fused dequant-GEMM: grid (N/BN=128, KSPLIT=8) = 1024 blocks
    gemm_fused<<<dim3(128, KSPLIT), 256, 0, stream>>>(Xb, (const float4*)U, q, expo, prt);
    // reduce: 2.09M elems / 4 = 524288 threads
    reduce_bias<<<2048, 256, 0, stream>>>((const float4*)prt, (const float4*)b,
                                          (float4*)out);
}